// Round 1
// baseline (16330.417 us; speedup 1.0000x reference)
//
#include <hip/hip_runtime.h>
#include <hip/hip_bf16.h>
#include <math.h>

// Model dims
#define NBLK 6
#define BS   200
#define NHID 1200
#define NINP 2400
#define TT   32
#define BZ   32
#define NTOK 16000
#define NG   4800      // NBLK*4*BS
#define ROWS 1024      // TT*BZ
#define L1D  1600      // 8 heads * 200

__device__ __forceinline__ float sigmoidf_(float x) { return 1.0f / (1.0f + expf(-x)); }

// ---------------------------------------------------------------------------
// Generic fp32 GEMM: C[M,N] = A[M,K] @ B (+bias1+bias2)
// BT=false: B is (K,N) row-major. BT=true: B is (N,K) row-major (dot of rows).
// a_idx: optional row gather (A row r = A + a_idx[r]*K) for fused embedding.
// Requires: M % 64 == 0, K % 8 == 0. N arbitrary (guarded).
// ---------------------------------------------------------------------------
template <bool BT>
__global__ __launch_bounds__(256) void gemm_kernel(
    const float* __restrict__ A, const float* __restrict__ B,
    const float* __restrict__ bias1, const float* __restrict__ bias2,
    float* __restrict__ C, int M, int N, int K, const int* __restrict__ a_idx)
{
    __shared__ __align__(16) float As[8][68];
    __shared__ __align__(16) float Bs[8][68];
    const int tid = threadIdx.x;
    const int tx = tid & 15, ty = tid >> 4;
    const int n0 = blockIdx.x * 64, m0 = blockIdx.y * 64;

    float acc[4][4] = {};

    for (int k0 = 0; k0 < K; k0 += 8) {
        // --- load A tile (64 rows x 8 k) ---
        {
            int idx = tid * 2;
            int mm = idx >> 3, kk = idx & 7;
            int row = m0 + mm;
            long arow = a_idx ? (long)a_idx[row] * K : (long)row * K;
            float2 v = *(const float2*)&A[arow + k0 + kk];
            As[kk][mm] = v.x;
            As[kk + 1][mm] = v.y;
        }
        // --- load B tile (8 k x 64 n) ---
        if constexpr (!BT) {
            int idx = tid * 2;
            int nn = idx & 63, kk = idx >> 6;
            int n = n0 + nn;
            float2 v = make_float2(0.f, 0.f);
            if (n < N) v = *(const float2*)&B[(long)(k0 + kk) * N + n];  // N even, n even
            Bs[kk][nn] = v.x;
            Bs[kk][nn + 1] = v.y;
        } else {
            int idx = tid * 2;
            int kk = idx & 7, nn = idx >> 3;
            int n = n0 + nn;
            float2 v = make_float2(0.f, 0.f);
            if (n < N) v = *(const float2*)&B[(long)n * K + k0 + kk];
            Bs[kk][nn] = v.x;
            Bs[kk + 1][nn] = v.y;
        }
        __syncthreads();
        #pragma unroll
        for (int kk = 0; kk < 8; kk++) {
            const float4 a4 = *(const float4*)&As[kk][ty * 4];
            const float4 b4 = *(const float4*)&Bs[kk][tx * 4];
            const float av[4] = {a4.x, a4.y, a4.z, a4.w};
            const float bv[4] = {b4.x, b4.y, b4.z, b4.w};
            #pragma unroll
            for (int i = 0; i < 4; i++)
                #pragma unroll
                for (int j = 0; j < 4; j++) acc[i][j] += av[i] * bv[j];
        }
        __syncthreads();
    }
    #pragma unroll
    for (int i = 0; i < 4; i++) {
        int row = m0 + ty * 4 + i;
        #pragma unroll
        for (int j = 0; j < 4; j++) {
            int col = n0 + tx * 4 + j;
            if (col < N) {
                float v = acc[i][j];
                if (bias1) v += bias1[col];
                if (bias2) v += bias2[col];
                C[(long)row * N + col] = v;
            }
        }
    }
}

// ---------------------------------------------------------------------------
// Layer-0 LSTM step: gates = GX(t rows; already has x@Wi^T + biases) + h@Wh^T
// grid (25, 6) = (j-tile, block k); 256 thr = (b in [0,32), jj in [0,8))
// ---------------------------------------------------------------------------
__global__ __launch_bounds__(256) void lstm0_kernel(
    const float* __restrict__ GX,    // (32, 4800)
    const float* __restrict__ hprev, // (32, 1200)
    float* __restrict__ c_io,        // (32, 1200) in/out
    const float* __restrict__ Wh,    // (6, 800, 200)
    float* __restrict__ h_out)       // (32, 1200) pre-attention
{
    __shared__ float h_s[200 * 33];
    const int k = blockIdx.y, jt = blockIdx.x, tid = threadIdx.x;
    for (int idx = tid; idx < 32 * 200; idx += 256) {
        int b = idx / 200, m = idx % 200;
        h_s[m * 33 + b] = hprev[b * NHID + k * BS + m];
    }
    __syncthreads();
    const int b = tid & 31, jj = tid >> 5;
    const int j = jt * 8 + jj;
    const float* w0 = Wh + (long)(k * 800 + j) * 200;
    const float* w1 = w0 + 200 * 200;
    const float* w2 = w0 + 400 * 200;
    const float* w3 = w0 + 600 * 200;
    float a0 = 0, a1 = 0, a2 = 0, a3 = 0;
    for (int m = 0; m < 200; m++) {
        float hv = h_s[m * 33 + b];
        a0 += hv * w0[m]; a1 += hv * w1[m]; a2 += hv * w2[m]; a3 += hv * w3[m];
    }
    const float* gx = GX + b * NG + k * 800;
    float gi = a0 + gx[j];
    float gf = a1 + gx[200 + j];
    float gg = a2 + gx[400 + j];
    float go = a3 + gx[600 + j];
    int o = b * NHID + k * BS + j;
    float cold = c_io[o];
    float cn = sigmoidf_(gf) * cold + sigmoidf_(gi) * tanhf(gg);
    float hn = sigmoidf_(go) * tanhf(cn);
    c_io[o] = cn;
    h_out[o] = hn;
}

// ---------------------------------------------------------------------------
// Layer-1 LSTM step: gates = inp@Wi^T + h@Wh^T + bih + bhh
// inp is (192, 2400) rows (b*6+k). grid (25, 6), 256 thr (b, jj)
// ---------------------------------------------------------------------------
__global__ __launch_bounds__(256) void lstm1_kernel(
    const float* __restrict__ inp, const float* __restrict__ hprev,
    float* __restrict__ c_io, const float* __restrict__ Wi,
    const float* __restrict__ Wh, const float* __restrict__ bih,
    const float* __restrict__ bhh, float* __restrict__ h_out)
{
    __shared__ float h_s[200 * 33];
    __shared__ float x_s[96 * 33];
    const int k = blockIdx.y, jt = blockIdx.x, tid = threadIdx.x;
    for (int idx = tid; idx < 32 * 200; idx += 256) {
        int b = idx / 200, m = idx % 200;
        h_s[m * 33 + b] = hprev[b * NHID + k * BS + m];
    }
    const int b = tid & 31, jj = tid >> 5;
    const int j = jt * 8 + jj;
    const float* wi0 = Wi + (long)(k * 800 + j) * NINP;
    const float* wi1 = wi0 + (long)200 * NINP;
    const float* wi2 = wi0 + (long)400 * NINP;
    const float* wi3 = wi0 + (long)600 * NINP;
    float a0 = 0, a1 = 0, a2 = 0, a3 = 0;
    for (int kt = 0; kt < NINP; kt += 96) {
        __syncthreads();
        for (int idx = tid; idx < 96 * 32; idx += 256) {
            int bb = idx / 96, m = idx % 96;
            x_s[m * 33 + bb] = inp[(long)(bb * 6 + k) * NINP + kt + m];
        }
        __syncthreads();
        for (int m = 0; m < 96; m++) {
            float xv = x_s[m * 33 + b];
            a0 += xv * wi0[kt + m]; a1 += xv * wi1[kt + m];
            a2 += xv * wi2[kt + m]; a3 += xv * wi3[kt + m];
        }
    }
    const float* w0 = Wh + (long)(k * 800 + j) * 200;
    const float* w1 = w0 + 200 * 200;
    const float* w2 = w0 + 400 * 200;
    const float* w3 = w0 + 600 * 200;
    for (int m = 0; m < 200; m++) {
        float hv = h_s[m * 33 + b];
        a0 += hv * w0[m]; a1 += hv * w1[m]; a2 += hv * w2[m]; a3 += hv * w3[m];
    }
    int nb = k * 800;
    float gi = a0 + bih[nb + j] + bhh[nb + j];
    float gf = a1 + bih[nb + 200 + j] + bhh[nb + 200 + j];
    float gg = a2 + bih[nb + 400 + j] + bhh[nb + 400 + j];
    float go = a3 + bih[nb + 600 + j] + bhh[nb + 600 + j];
    int o = b * NHID + k * BS + j;
    float cold = c_io[o];
    float cn = sigmoidf_(gf) * cold + sigmoidf_(gi) * tanhf(gg);
    float hn = sigmoidf_(go) * tanhf(cn);
    c_io[o] = cn;
    h_out[o] = hn;
}

// ---------------------------------------------------------------------------
// Small self-attention (nh=4, dk=dv=16) + residual + LN over 200. grid=32 (b)
// ---------------------------------------------------------------------------
__global__ __launch_bounds__(256) void att_small_kernel(
    const float* __restrict__ h_in, float* __restrict__ h_out,
    const float* __restrict__ mq, const float* __restrict__ mk,
    const float* __restrict__ mv, const float* __restrict__ mfc,
    const float* __restrict__ mg, const float* __restrict__ mb)
{
    __shared__ float hb[1200];
    __shared__ float qh[384], kh[384], vh[384];
    __shared__ float att[144];
    __shared__ float outp[384];
    __shared__ float o2[1200];
    __shared__ float mu_s[6], rs_s[6];
    const int b = blockIdx.x, tid = threadIdx.x;
    for (int i = tid; i < 1200; i += 256) hb[i] = h_in[b * NHID + i];
    __syncthreads();
    for (int id = tid; id < 1152; id += 256) {
        int which = id / 384, r = id % 384;
        int l = r >> 6, hd = r & 63;
        const float* Mw = which == 0 ? mq : (which == 1 ? mk : mv);
        const float* hr = &hb[l * 200];
        float s = 0;
        for (int jx = 0; jx < 200; jx++) s += hr[jx] * Mw[jx * 64 + hd];
        float* dst = which == 0 ? qh : (which == 1 ? kh : vh);
        dst[r] = s;
    }
    __syncthreads();
    for (int id = tid; id < 144; id += 256) {
        int h = id / 36, r = id % 36, q = r / 6, kk = r % 6;
        float s = 0;
        for (int d = 0; d < 16; d++) s += qh[q * 64 + h * 16 + d] * kh[kk * 64 + h * 16 + d];
        att[(h * 6 + q) * 6 + kk] = s * 0.25f;  // 1/sqrt(16)
    }
    __syncthreads();
    if (tid < 24) {
        float* a = &att[tid * 6];
        float mx = a[0];
        for (int i = 1; i < 6; i++) mx = fmaxf(mx, a[i]);
        float sm = 0;
        for (int i = 0; i < 6; i++) { a[i] = expf(a[i] - mx); sm += a[i]; }
        float inv = 1.f / sm;
        for (int i = 0; i < 6; i++) a[i] *= inv;
    }
    __syncthreads();
    for (int id = tid; id < 384; id += 256) {
        int q = id >> 6, hd = id & 63, h = hd >> 4;
        float s = 0;
        for (int kk = 0; kk < 6; kk++) s += att[(h * 6 + q) * 6 + kk] * vh[kk * 64 + hd];
        outp[id] = s;
    }
    __syncthreads();
    for (int id = tid; id < 1200; id += 256) {
        int q = id / 200, jx = id % 200;
        float s = 0;
        for (int d = 0; d < 64; d++) s += outp[q * 64 + d] * mfc[d * 200 + jx];
        o2[id] = s + hb[id];  // residual
    }
    __syncthreads();
    if (tid < 6) {
        float s = 0, s2 = 0;
        for (int jx = 0; jx < 200; jx++) { float v = o2[tid * 200 + jx]; s += v; s2 += v * v; }
        float mu = s / 200.f;
        float var = s2 / 200.f - mu * mu;
        mu_s[tid] = mu;
        rs_s[tid] = 1.0f / sqrtf(var + 1e-5f);
    }
    __syncthreads();
    for (int id = tid; id < 1200; id += 256) {
        int q = id / 200, jx = id % 200;
        h_out[b * NHID + id] = (o2[id] - mu_s[q]) * rs_s[q] * mg[jx] + mb[jx];
    }
}

// ---------------------------------------------------------------------------
// Layer-1 attention: scores (8 heads, dk=200) + softmax + att@V. grid=32 (b)
// ---------------------------------------------------------------------------
__global__ __launch_bounds__(256) void att1_kernel(
    const float* __restrict__ QH,  // (192,1600) rows (b*6+q)
    const float* __restrict__ KH,  // rows (b*6+k) for this t
    const float* __restrict__ VH,
    float* __restrict__ attV)      // (192,1600)
{
    __shared__ float att[288];
    const int b = blockIdx.x, tid = threadIdx.x;
    const float* qb = QH + b * 9600;
    const float* kb = KH + b * 9600;
    const float* vb = VH + b * 9600;
    for (int id = tid; id < 288; id += 256) {
        int h = id / 36, r = id % 36, q = r / 6, kk = r % 6;
        const float* qr = qb + q * L1D + h * 200;
        const float* kr = kb + kk * L1D + h * 200;
        float s = 0;
        for (int d = 0; d < 200; d++) s += qr[d] * kr[d];
        att[(h * 6 + q) * 6 + kk] = s * 0.07071067811865475f;  // 1/sqrt(200)
    }
    __syncthreads();
    if (tid < 48) {
        float* a = &att[tid * 6];
        float mx = a[0];
        for (int i = 1; i < 6; i++) mx = fmaxf(mx, a[i]);
        float sm = 0;
        for (int i = 0; i < 6; i++) { a[i] = expf(a[i] - mx); sm += a[i]; }
        float inv = 1.f / sm;
        for (int i = 0; i < 6; i++) a[i] *= inv;
    }
    __syncthreads();
    for (int id = tid; id < 9600; id += 256) {
        int q = id / L1D, hd = id % L1D, h = hd / 200;
        float s = 0;
        for (int kk = 0; kk < 6; kk++) s += att[(h * 6 + q) * 6 + kk] * vb[kk * L1D + hd];
        attV[b * 9600 + id] = s;
    }
}

// ---------------------------------------------------------------------------
// LayerNorm over n columns. grid = rows, 256 threads.
// ---------------------------------------------------------------------------
__global__ __launch_bounds__(256) void ln_kernel(
    const float* __restrict__ X, float* __restrict__ Y,
    const float* __restrict__ g, const float* __restrict__ bta, int n)
{
    const int row = blockIdx.x, tid = threadIdx.x;
    const float* xr = X + (long)row * n;
    float s = 0, s2 = 0;
    for (int i = tid; i < n; i += 256) { float v = xr[i]; s += v; s2 += v * v; }
    for (int off = 32; off; off >>= 1) { s += __shfl_down(s, off); s2 += __shfl_down(s2, off); }
    __shared__ float rs[8], rq[8];
    int wid = tid >> 6, lane = tid & 63;
    if (lane == 0) { rs[wid] = s; rq[wid] = s2; }
    __syncthreads();
    if (tid == 0) {
        float a = 0, a2 = 0;
        for (int w = 0; w < 4; w++) { a += rs[w]; a2 += rq[w]; }
        float mu = a / n;
        float var = a2 / n - mu * mu;
        rs[0] = mu;
        rq[0] = 1.0f / sqrtf(var + 1e-5f);
    }
    __syncthreads();
    float mu = rs[0], rstd = rq[0];
    for (int i = tid; i < n; i += 256) Y[(long)row * n + i] = (xr[i] - mu) * rstd * g[i] + bta[i];
}

// ---------------------------------------------------------------------------
extern "C" void kernel_launch(void* const* d_in, const int* in_sizes, int n_in,
                              void* d_out, int out_size, void* d_ws, size_t ws_size,
                              hipStream_t stream)
{
    const int*   tokens = (const int*)  d_in[0];
    const float* h0     = (const float*)d_in[1];
    const float* c0     = (const float*)d_in[2];
    const float* emb    = (const float*)d_in[3];
    const float* Wi     = (const float*)d_in[4];
    const float* Wh     = (const float*)d_in[5];
    const float* bih    = (const float*)d_in[6];
    const float* bhh    = (const float*)d_in[7];
    const float* mq     = (const float*)d_in[8];
    const float* mk     = (const float*)d_in[9];
    const float* mv     = (const float*)d_in[10];
    const float* mfc    = (const float*)d_in[11];
    const float* mg     = (const float*)d_in[12];
    const float* mb     = (const float*)d_in[13];
    const float* lq     = (const float*)d_in[14];
    const float* lk     = (const float*)d_in[15];
    const float* lv     = (const float*)d_in[16];
    const float* lfc    = (const float*)d_in[17];
    const float* lg     = (const float*)d_in[18];
    const float* lb     = (const float*)d_in[19];
    const float* dec_w  = (const float*)d_in[20];
    const float* dec_b  = (const float*)d_in[21];
    float* out = (float*)d_out;

    // workspace carve-up (floats)
    float* p = (float*)d_ws;
    float* GX0  = p; p += (long)ROWS * NG;        // 1024*4800
    float* out0 = p; p += (long)ROWS * NHID;      // 1024*1200
    float* out1 = p; p += (long)ROWS * NHID;
    float* KH1  = p; p += (long)ROWS * 6 * L1D;   // 6144*1600
    float* VH1  = p; p += (long)ROWS * 6 * L1D;
    float* QH   = p; p += 192 * L1D;
    float* attV = p; p += 192 * L1D;
    float* FCb  = p; p += 192 * NINP;
    float* inp  = p; p += 192 * NINP;
    float* htmp = p; p += BZ * NHID;
    float* cb0  = p; p += BZ * NHID;
    float* cb1  = p; p += BZ * NHID;

    const int ST = BZ * NHID;  // 38400 floats per (32,1200) state

    // init cell states from c0
    hipMemcpyAsync(cb0, c0,        ST * sizeof(float), hipMemcpyDeviceToDevice, stream);
    hipMemcpyAsync(cb1, c0 + ST,   ST * sizeof(float), hipMemcpyDeviceToDevice, stream);

    // GX0 = emb[tokens] @ Wi^T + bih + bhh   (fused embedding gather via a_idx)
    gemm_kernel<true><<<dim3(NG / 64, ROWS / 64), 256, 0, stream>>>(
        emb, Wi, bih, bhh, GX0, ROWS, NG, NINP, tokens);

    // ---- Phase A: layer-0 scan ----
    for (int t = 0; t < TT; t++) {
        const float* hp = (t == 0) ? h0 : out0 + (t - 1) * ST;
        lstm0_kernel<<<dim3(25, 6), 256, 0, stream>>>(
            GX0 + (long)t * BZ * NG, hp, cb0, Wh, htmp);
        att_small_kernel<<<BZ, 256, 0, stream>>>(htmp, out0 + t * ST, mq, mk, mv, mfc, mg, mb);
    }

    // KH1/VH1 = out0 (as (6144,200)) @ lk / lv
    gemm_kernel<false><<<dim3(L1D / 64, (ROWS * 6) / 64), 256, 0, stream>>>(
        out0, lk, nullptr, nullptr, KH1, ROWS * 6, L1D, BS, nullptr);
    gemm_kernel<false><<<dim3(L1D / 64, (ROWS * 6) / 64), 256, 0, stream>>>(
        out0, lv, nullptr, nullptr, VH1, ROWS * 6, L1D, BS, nullptr);

    // ---- Phase B: layer-1 scan ----
    for (int t = 0; t < TT; t++) {
        const float* hp = (t == 0) ? h0 + ST : out1 + (t - 1) * ST;
        // QH = h (as (192,200)) @ lq
        gemm_kernel<false><<<dim3(L1D / 64, 3), 256, 0, stream>>>(
            hp, lq, nullptr, nullptr, QH, 192, L1D, BS, nullptr);
        att1_kernel<<<BZ, 256, 0, stream>>>(
            QH, KH1 + (long)t * BZ * 6 * L1D, VH1 + (long)t * BZ * 6 * L1D, attV);
        // FC = attV @ lfc  (192,2400 K=1600)
        gemm_kernel<false><<<dim3((NINP + 63) / 64, 3), 256, 0, stream>>>(
            attV, lfc, nullptr, nullptr, FCb, 192, NINP, L1D, nullptr);
        ln_kernel<<<192, 256, 0, stream>>>(FCb, inp, lg, lb, NINP);
        lstm1_kernel<<<dim3(25, 6), 256, 0, stream>>>(inp, hp, cb1, Wi, Wh, bih, bhh, htmp);
        att_small_kernel<<<BZ, 256, 0, stream>>>(htmp, out1 + t * ST, mq, mk, mv, mfc, mg, mb);
    }

    // decode: out1 (1024,1200) @ dec_w^T + dec_b -> d_out (1024,16000)
    gemm_kernel<true><<<dim3(NTOK / 64, ROWS / 64), 256, 0, stream>>>(
        out1, dec_w, dec_b, nullptr, out, ROWS, NTOK, NHID, nullptr);

    // final states: [hf0; hf1] then [cf0; cf1]
    long off = (long)ROWS * NTOK;
    hipMemcpyAsync(out + off,          out0 + 31 * ST, ST * sizeof(float), hipMemcpyDeviceToDevice, stream);
    hipMemcpyAsync(out + off + ST,     out1 + 31 * ST, ST * sizeof(float), hipMemcpyDeviceToDevice, stream);
    hipMemcpyAsync(out + off + 2 * ST, cb0,            ST * sizeof(float), hipMemcpyDeviceToDevice, stream);
    hipMemcpyAsync(out + off + 3 * ST, cb1,            ST * sizeof(float), hipMemcpyDeviceToDevice, stream);
}